// Round 3
// baseline (43.255 us; speedup 1.0000x reference)
//
#include <hip/hip_runtime.h>

// KL(p||q) for diagonal Gaussians, sigma_* are log-variances.
// out[b] = 0.5 * sum_d[ exp(sp-sq) + (mu_q-mu_p)^2*exp(-sq) + sq - sp - 1 ]
// B=16384, D=1024, f32 in/out. Memory-bound: 256 MB in / 64 KB out.
//
// L3 partitioning trick: inputs total exactly 256 MB = L3 capacity -> LRU
// thrash (~49% hit, measured r1). Stream mu_q/mu_p with non-temporal loads
// so sigma_q/sigma_p (128 MB) stay L3-resident across graph replays.
// Note: __builtin_nontemporal_load needs a NATIVE vector type, not float4
// (HIP_vector_type) — use ext_vector_type.

constexpr int D_DIM = 1024;

typedef float f32x4 __attribute__((ext_vector_type(4)));

__global__ __launch_bounds__(256) void _KLD_MVNx2_kernel(
    const float* __restrict__ mu_q,
    const float* __restrict__ sigma_q,
    const float* __restrict__ mu_p,
    const float* __restrict__ sigma_p,
    float* __restrict__ out,
    int B)
{
    const int row = blockIdx.x;
    if (row >= B) return;
    const int tid = threadIdx.x;

    // Each of 256 threads handles 4 consecutive floats: 256*4 = 1024 = D.
    const size_t base = (size_t)row * D_DIM + (size_t)tid * 4;

    // Non-temporal (streaming) loads for the mu arrays: don't retain in L3.
    const f32x4 mq = __builtin_nontemporal_load(
        reinterpret_cast<const f32x4*>(mu_q + base));
    const f32x4 mp = __builtin_nontemporal_load(
        reinterpret_cast<const f32x4*>(mu_p + base));
    // Normal loads for sigma arrays: these should stay L3-resident.
    const f32x4 sq = *reinterpret_cast<const f32x4*>(sigma_q + base);
    const f32x4 sp = *reinterpret_cast<const f32x4*>(sigma_p + base);

    float s = 0.0f;
    #pragma unroll
    for (int j = 0; j < 4; ++j) {
        float d = mq[j] - mp[j];
        s += __expf(sp[j] - sq[j]) + d * d * __expf(-sq[j]) + (sq[j] - sp[j]);
    }
    s -= 4.0f;  // the "-1" per element, 4 elements per thread

    // Wave (64-lane) reduction.
    #pragma unroll
    for (int off = 32; off > 0; off >>= 1)
        s += __shfl_down(s, off);

    __shared__ float part[4];
    const int lane = tid & 63;
    const int wv   = tid >> 6;
    if (lane == 0) part[wv] = s;
    __syncthreads();

    if (tid == 0)
        out[row] = 0.5f * (part[0] + part[1] + part[2] + part[3]);
}

extern "C" void kernel_launch(void* const* d_in, const int* in_sizes, int n_in,
                              void* d_out, int out_size, void* d_ws, size_t ws_size,
                              hipStream_t stream) {
    const float* mu_q    = (const float*)d_in[0];
    const float* sigma_q = (const float*)d_in[1];
    const float* mu_p    = (const float*)d_in[2];
    const float* sigma_p = (const float*)d_in[3];
    float* out = (float*)d_out;

    const int B = out_size;  // 16384 rows
    _KLD_MVNx2_kernel<<<B, 256, 0, stream>>>(mu_q, sigma_q, mu_p, sigma_p, out, B);
}

// Round 4
// 42.366 us; speedup vs baseline: 1.0210x; 1.0210x over previous
//
#include <hip/hip_runtime.h>

// KL(p||q) for diagonal Gaussians, sigma_* are log-variances.
// out[b] = 0.5 * sum_d[ exp(sp-sq) + (mu_q-mu_p)^2*exp(-sq) + sq - sp - 1 ]
// B=16384, D=1024, f32 in/out. Memory-bound: 256 MB read / 64 KB written.
//
// r1-r3 findings: delivered BW caps at ~6 TB/s whether bytes come from L3 or
// HBM (nt-load partitioning changed nothing); L3 lever is dead. This round:
// wave-per-row (one 64-lane wave owns a full 1024-float row) -> 16 independent
// float4 loads in flight per thread, no __syncthreads, no LDS, 4x fewer blocks.

constexpr int D_DIM = 1024;

typedef float f32x4 __attribute__((ext_vector_type(4)));

__global__ __launch_bounds__(256) void _KLD_MVNx2_kernel(
    const float* __restrict__ mu_q,
    const float* __restrict__ sigma_q,
    const float* __restrict__ mu_p,
    const float* __restrict__ sigma_p,
    float* __restrict__ out,
    int B)
{
    const int wv   = threadIdx.x >> 6;            // wave id in block: 0..3
    const int lane = threadIdx.x & 63;
    const int row  = blockIdx.x * 4 + wv;         // one row per wave
    if (row >= B) return;

    const size_t rb = (size_t)row * D_DIM;

    // Row = 1024 floats = 4 chunks of 256; lane i takes floats [c*256+i*4 ..+3].
    // Issue all 16 loads (4 chunks x 4 arrays) before any compute: deep MLP.
    f32x4 mq[4], sq[4], mp[4], sp[4];
    #pragma unroll
    for (int c = 0; c < 4; ++c) {
        const size_t idx = rb + (size_t)c * 256 + (size_t)lane * 4;
        mq[c] = *reinterpret_cast<const f32x4*>(mu_q    + idx);
        mp[c] = *reinterpret_cast<const f32x4*>(mu_p    + idx);
        sq[c] = *reinterpret_cast<const f32x4*>(sigma_q + idx);
        sp[c] = *reinterpret_cast<const f32x4*>(sigma_p + idx);
    }

    float s = -16.0f;  // the "-1" per element, 16 elements per thread
    #pragma unroll
    for (int c = 0; c < 4; ++c) {
        #pragma unroll
        for (int j = 0; j < 4; ++j) {
            const float d = mq[c][j] - mp[c][j];
            s += __expf(sp[c][j] - sq[c][j])
               + d * d * __expf(-sq[c][j])
               + (sq[c][j] - sp[c][j]);
        }
    }

    // Wave (64-lane) reduction; no LDS, no barrier.
    #pragma unroll
    for (int off = 32; off > 0; off >>= 1)
        s += __shfl_down(s, off);

    if (lane == 0)
        out[row] = 0.5f * s;
}

extern "C" void kernel_launch(void* const* d_in, const int* in_sizes, int n_in,
                              void* d_out, int out_size, void* d_ws, size_t ws_size,
                              hipStream_t stream) {
    const float* mu_q    = (const float*)d_in[0];
    const float* sigma_q = (const float*)d_in[1];
    const float* mu_p    = (const float*)d_in[2];
    const float* sigma_p = (const float*)d_in[3];
    float* out = (float*)d_out;

    const int B = out_size;                // 16384 rows
    const int blocks = (B + 3) / 4;        // 4 rows (waves) per 256-thread block
    _KLD_MVNx2_kernel<<<blocks, 256, 0, stream>>>(mu_q, sigma_q, mu_p, sigma_p, out, B);
}